// Round 1
// baseline (2937.338 us; speedup 1.0000x reference)
//
#include <hip/hip_runtime.h>

#define T_STEPS 1000
#define IN 13
#define HID 32
#define ELEMS 4
#define GRPSTEPS 4
#define GRPFLOATS (GRPSTEPS * IN * ELEMS)          // 208 floats per group
#define NGRP (T_STEPS / GRPSTEPS)                  // 250
#define ZROWS 46                                   // 13 x-rows + 32 h-rows + 1 zero pad row
#define ZSLOT (ZROWS * ELEMS)                      // 184 doubles per slot

// ---------- double-precision exp/sigmoid — IDENTICAL numerics to prior rounds ----------
__device__ __forceinline__ double exp_d(double u) {
    const double INV_LN2 = 1.4426950408889634074;
    const double LN2_HI  = 6.93147180369123816490e-01;
    const double LN2_LO  = 1.90821492927058770002e-10;
    const double MAGIC   = 6755399441055744.0;          // 1.5 * 2^52
    double s  = fma(u, INV_LN2, MAGIC);
    int    n  = (int)__double2loint(s);
    double nd = s - MAGIC;
    double r  = fma(nd, -LN2_HI, u);
    r = fma(nd, -LN2_LO, r);
    double p = 2.4801587301587301587e-5;
    p = fma(p, r, 1.9841269841269841270e-4);
    p = fma(p, r, 1.3888888888888888889e-3);
    p = fma(p, r, 8.3333333333333333333e-3);
    p = fma(p, r, 4.1666666666666666667e-2);
    p = fma(p, r, 1.6666666666666666667e-1);
    p = fma(p, r, 0.5);
    p = fma(p, r, 1.0);
    p = fma(p, r, 1.0);
    return __hiloint2double(__double2hiint(p) + (n << 20), __double2loint(p));
}

__device__ __forceinline__ double sigmoid_d(double x) {
    double u = fmin(fmax(-x, -30.0), 30.0);
    double e = exp_d(u);
    double d = 1.0 + e;
    double r0 = (double)__builtin_amdgcn_rcpf((float)d);
    return r0 * fma(-d, r0, 2.0);
}

__device__ __forceinline__ double act_fn(double x, bool istanh) {
    double pre = istanh ? (x + x) : x;
    double sv  = sigmoid_d(pre);
    return istanh ? fma(2.0, sv, -1.0) : sv;
}

// Block = 512 threads = 8 waves, FOUR batch elements. Waves 0-3: layer0; waves 4-7:
// layer1 (pipelined one step behind). Each gate row is SPLIT across a lane pair
// (half = (lane&7)>>2) so per-lane weights are <=32 f64 (64 VGPRs) -> fits the
// 128-VGPR budget for 4 waves/SIMD (launch_bounds(512,4) => 2 blocks/CU, 16 waves/CU).
//
// LDS operand layout: zbuf[8 slots][46 rows][4 elems] f64.
//   rows 0..12  = x_t      (slot = t & 7, staged in groups of 4 steps, 4 ahead)
//   rows 13..44 = h0_{t-1} (L0 at iter k WRITES its h into slot (k+1)&7, so slot s
//                           always holds the contiguous operand [x_s | h0_{s-1}])
//   row  45     = zero pad (lets half1's 22-length dot run a uniform 23-iter loop
//                           with w[22] = 0)
// This makes both halves' dot loops branch-free: per-lane base pointer + uniform trip
// count (L0: 23 iters, split 23/22; L1: 32 iters, half0 = Wih1 @ h0, half1 = Whh1 @ h1).
//
// After the dot: pair-combine via shfl_xor(4); acts split across the pair (each lane
// 2 gate activations for 2 elems); then xor1/xor2 exchanges give every lane the full
// (i,f,g,o) of one element (x2 duplicated) for the cell update; lanes with (g&2)==0
// write h back.
__global__ __launch_bounds__(512, 4)
void lstm_fused(const float* __restrict__ X,
                const float* __restrict__ Wih0, const float* __restrict__ Whh0,
                const float* __restrict__ bih0, const float* __restrict__ bhh0,
                const float* __restrict__ Wih1, const float* __restrict__ Whh1,
                const float* __restrict__ bih1, const float* __restrict__ bhh1,
                const float* __restrict__ Wc1,  const float* __restrict__ bc1,
                const float* __restrict__ Wc2,  const float* __restrict__ bc2,
                float* __restrict__ out)
{
    const int tid  = threadIdx.x;
    const int wave = tid >> 6;
    const bool isL1 = (wave >= 4);
    const int L    = tid & 255;                 // layer-local thread 0..255
    const int u    = L >> 3;                    // unit 0..31
    const int r    = L & 7;
    const int g    = r & 3;                     // 0=i 1=f 2=g 3=o
    const int hh   = r >> 2;                    // row half 0/1
    const int row  = (g << 5) + u;              // gate row 0..127
    const int eA   = blockIdx.x * ELEMS;

    __shared__ __align__(16) double zbuf[8][ZROWS][ELEMS];
    __shared__ __align__(16) double h1buf[2][HID][ELEMS];
    __shared__ __align__(16) double hidbuf[HID][ELEMS];

    // ---- per-lane HALF-row of weights (max 32 f64 = 64 VGPRs) ----
    double w[32];
    #pragma unroll
    for (int i = 0; i < 32; ++i) w[i] = 0.0;
    double bias = 0.0;
    if (!isL1) {
        if (hh == 0) {
            #pragma unroll
            for (int i = 0; i < IN; ++i)  w[i]      = (double)Wih0[row*IN + i];
            #pragma unroll
            for (int j = 0; j < 10; ++j)  w[IN + j] = (double)Whh0[row*HID + j];
            bias = (double)bih0[row] + (double)bhh0[row];
        } else {
            #pragma unroll
            for (int j = 0; j < 22; ++j)  w[j] = (double)Whh0[row*HID + 10 + j];
            // w[22] stays 0.0 -> multiplies the zero pad row
        }
    } else {
        if (hh == 0) {
            #pragma unroll
            for (int j = 0; j < HID; ++j) w[j] = (double)Wih1[row*HID + j];
            bias = (double)bih1[row] + (double)bhh1[row];
        } else {
            #pragma unroll
            for (int j = 0; j < HID; ++j) w[j] = (double)Whh1[row*HID + j];
        }
    }

    // ---- zero h-rows + pad rows of all 8 slots (x rows are staged, never pre-read)
    for (int i = tid; i < 8 * ZSLOT; i += 512) {
        int rowe = i % ZSLOT;
        if (rowe >= IN * ELEMS) ((double*)zbuf)[i] = 0.0;
    }
    if (tid < 128) ((double*)h1buf)[tid] = 0.0;     // h1[-1] = 0 (buffer parity 0)

    // ---- x staging: 104 stagers, float2 each; writes go straight into zbuf x-rows
    const bool stager = (tid < GRPFLOATS / 2);      // tid < 104 (waves 0-1, L0)
    int off0 = 0, off1 = 0;
    const float* xg = nullptr;
    float2 xreg = make_float2(0.f, 0.f);
    if (stager) {
        int f0 = tid * 2, f1 = f0 + 1;
        int e0 = f0 / (GRPSTEPS * IN); int r0 = f0 % (GRPSTEPS * IN);
        int t0 = r0 / IN, i0 = r0 % IN;
        int r1 = f1 % (GRPSTEPS * IN);              // same elem: per-elem span 52, f0 even
        int t1 = r1 / IN, i1 = r1 % IN;
        off0 = t0 * ZSLOT + i0 * ELEMS + e0;
        off1 = t1 * ZSLOT + i1 * ELEMS + e0;
        xg = X + (size_t)(eA + e0) * (T_STEPS * IN) + (size_t)r0;
        float2 x0 = *(const float2*)xg;             // group 0 -> slots 0..3
        ((double*)zbuf)[off0] = (double)x0.x;
        ((double*)zbuf)[off1] = (double)x0.y;
        xreg = *(const float2*)(xg + GRPSTEPS * IN);// prefetch group 1
    }
    __syncthreads();

    double cst = 0.0;   // cell state of owned element (duplicated across the xor2 pair)

    #pragma unroll 1
    for (int k = 0; k <= T_STEPS; ++k) {
        const int p   = k & 1;
        const int grp = k >> 2;
        const int ph  = k & 3;

        if (ph == 0 && stager) {
            if (grp + 1 < NGRP) {
                const int base = ((grp + 1) & 1) ? 4 * ZSLOT : 0;
                ((double*)zbuf)[base + off0] = (double)xreg.x;
                ((double*)zbuf)[base + off1] = (double)xreg.y;
            }
            if (grp + 2 < NGRP) xreg = *(const float2*)(xg + (size_t)(grp + 2) * GRPSTEPS * IN);
        }

        const bool active = isL1 ? (k >= 1) : (k < T_STEPS);
        if (active) {
            double a0 = bias, a1 = bias, a2 = bias, a3 = bias;
            if (!isL1) {
                // uniform 23-iter loop; half0 covers [x | h0[0..9]], half1 covers h0[10..31]+pad
                const double* zp = &zbuf[k & 7][0][0] + (hh ? 23 * ELEMS : 0);
                #pragma unroll
                for (int i = 0; i < 23; ++i) {
                    double q0 = zp[i*4+0], q1 = zp[i*4+1], q2 = zp[i*4+2], q3 = zp[i*4+3];
                    a0 = fma(w[i], q0, a0); a1 = fma(w[i], q1, a1);
                    a2 = fma(w[i], q2, a2); a3 = fma(w[i], q3, a3);
                }
            } else {
                // half0: Wih1 . h0[k-1] (zbuf slot k&7 rows 13..44); half1: Whh1 . h1[k-2]
                const double* zp = hh ? &h1buf[p ^ 1][0][0] : &zbuf[k & 7][13][0];
                #pragma unroll
                for (int j = 0; j < HID; ++j) {
                    double q0 = zp[j*4+0], q1 = zp[j*4+1], q2 = zp[j*4+2], q3 = zp[j*4+3];
                    a0 = fma(w[j], q0, a0); a1 = fma(w[j], q1, a1);
                    a2 = fma(w[j], q2, a2); a3 = fma(w[j], q3, a3);
                }
            }

            // pair-combine (commutative add -> both halves bit-identical)
            a0 += __shfl_xor(a0, 4);
            a1 += __shfl_xor(a1, 4);
            a2 += __shfl_xor(a2, 4);
            a3 += __shfl_xor(a3, 4);

            // acts split across the pair: half0 -> elems 0,1 ; half1 -> elems 2,3
            const bool istanh = (g == 2);
            double x0 = hh ? a2 : a0;
            double x1 = hh ? a3 : a1;
            double v0 = act_fn(x0, istanh);
            double v1 = act_fn(x1, istanh);

            // xor1: gather gate pair (2G, 2G+1) of elem e1 = 2*hh + (g&1)
            double t0 = __shfl_xor(v0, 1);
            double t1 = __shfl_xor(v1, 1);
            const bool odd = (g & 1);
            double u0 = odd ? t1 : v0;
            double u1 = odd ? v1 : t0;
            // xor2: complete the gate set (partner has the other gate pair, same elem)
            double t2 = __shfl_xor(u0, 2);
            double t3 = __shfl_xor(u1, 2);
            const bool gb = (g & 2);
            double gi = gb ? t2 : u0;
            double gf = gb ? t3 : u1;
            double gg = gb ? u0 : t2;
            double go = gb ? u1 : t3;

            cst = fma(gf, cst, gi * gg);
            double th = act_fn(cst, true);              // tanh(c)
            double hval = go * th;

            const int e1 = (hh << 1) | (g & 1);
            if (!gb) {
                if (!isL1) zbuf[(k + 1) & 7][13 + u][e1] = hval;  // pairs with x_{k+1}
                else       h1buf[p][u][e1] = hval;
            }
        }
        __syncthreads();
    }

    // ---- classifier head (f64): hidden = relu(Wc1 @ h1 + bc1); out = Wc2 @ hidden + bc2
    if (tid < 128) {
        const int e = tid >> 5, j = tid & 31;
        double acc = (double)bc1[j];
        #pragma unroll
        for (int jj = 0; jj < HID; ++jj)
            acc = fma((double)Wc1[j*HID + jj], h1buf[T_STEPS & 1][jj][e], acc);
        hidbuf[j][e] = fmax(acc, 0.0);
    }
    __syncthreads();
    if (tid < 3 * ELEMS) {
        const int e = tid / 3, c = tid % 3;
        double v = (double)bc2[c];
        #pragma unroll
        for (int j = 0; j < HID; ++j)
            v = fma((double)Wc2[c*HID + j], hidbuf[j][e], v);
        out[(eA + e) * 3 + c] = (float)v;
    }
}

extern "C" void kernel_launch(void* const* d_in, const int* in_sizes, int n_in,
                              void* d_out, int out_size, void* d_ws, size_t ws_size,
                              hipStream_t stream) {
    const float* X    = (const float*)d_in[0];
    const float* Wih0 = (const float*)d_in[1];
    const float* Whh0 = (const float*)d_in[2];
    const float* bih0 = (const float*)d_in[3];
    const float* bhh0 = (const float*)d_in[4];
    const float* Wih1 = (const float*)d_in[5];
    const float* Whh1 = (const float*)d_in[6];
    const float* bih1 = (const float*)d_in[7];
    const float* bhh1 = (const float*)d_in[8];
    const float* Wc1  = (const float*)d_in[9];
    const float* bc1  = (const float*)d_in[10];
    const float* Wc2  = (const float*)d_in[11];
    const float* bc2  = (const float*)d_in[12];

    lstm_fused<<<512, 512, 0, stream>>>(X, Wih0, Whh0, bih0, bhh0,
                                        Wih1, Whh1, bih1, bhh1,
                                        Wc1, bc1, Wc2, bc2, (float*)d_out);
}